// Round 4
// baseline (115.512 us; speedup 1.0000x reference)
//
#include <hip/hip_runtime.h>
#include <hip/hip_bf16.h>

// Problem constants (fixed by setup_inputs): C=64 cliques, S=16, D=256, P=65536
#define NC 64
#define NS 16
#define ND 256
#define NP 65536
#define EPS 1e-8f

// ---------------------------------------------------------------------------
// Kernel 1: per-clique cosine-similarity attention weights.
// One block per clique, 256 threads; thread t = i*16 + j computes dot(x_i,x_j).
// Row softmax via __shfl_xor within the 16-lane group (t layout keeps each
// row i inside one contiguous 16-lane group of the wave64).
// ---------------------------------------------------------------------------
__global__ __launch_bounds__(256) void coexpert_weights(
    const float* __restrict__ reps,   // [C, S, D]
    float* __restrict__ w)            // [C, S, S]
{
    const int c = blockIdx.x;
    const int t = threadIdx.x;

    __shared__ float xs[NS][ND];      // 16 KiB
    __shared__ float norms[NS];

    // Cooperative load of this clique's reps: 4096 floats / 256 threads.
    const float* xc = reps + (size_t)c * NS * ND;
    #pragma unroll
    for (int k = t; k < NS * ND; k += 256)
        xs[k >> 8][k & (ND - 1)] = xc[k];
    __syncthreads();

    const int i = t >> 4;
    const int j = t & 15;

    // dot(x_i, x_j) with float4 LDS reads
    float dot = 0.f;
    #pragma unroll 8
    for (int d = 0; d < ND; d += 4) {
        float4 a = *reinterpret_cast<const float4*>(&xs[i][d]);
        float4 b = *reinterpret_cast<const float4*>(&xs[j][d]);
        dot += a.x * b.x + a.y * b.y + a.z * b.z + a.w * b.w;
    }

    // Diagonal threads publish norms.
    if (i == j) norms[i] = sqrtf(dot);
    __syncthreads();

    float sim = dot / (norms[i] * norms[j] + EPS);

    // Row softmax over j (16-lane group reduce; xor masks < 16 stay in-group).
    float m = sim;
    #pragma unroll
    for (int off = 1; off < 16; off <<= 1)
        m = fmaxf(m, __shfl_xor(m, off));
    float e = expf(sim - m);
    float s = e;
    #pragma unroll
    for (int off = 1; off < 16; off <<= 1)
        s += __shfl_xor(s, off);

    w[(size_t)c * NS * NS + t] = e / s;
}

// ---------------------------------------------------------------------------
// Kernel 2: out[c,i,p] = sum_j w[c,i,j] * params[c,j,p]
// Memory-bound streaming: each thread owns 4 consecutive p's (float4).
// Loads the 16 j-values once (each params element read exactly once
// grid-wide), then emits all 16 i-outputs. Perfectly coalesced.
// ---------------------------------------------------------------------------
__global__ __launch_bounds__(256) void coexpert_agg(
    const float* __restrict__ params, // [C, S, P]
    const float* __restrict__ w,      // [C, S, S]
    float* __restrict__ out)          // [C, S, P]
{
    const int chunk = blockIdx.x;     // 64 chunks of 1024 p's
    const int c     = blockIdx.y;     // 64 cliques
    const int t     = threadIdx.x;

    __shared__ float ws[NS][NS];
    ws[t >> 4][t & 15] = w[(size_t)c * NS * NS + t];
    __syncthreads();

    const size_t base = (size_t)c * NS * NP + (size_t)chunk * 1024 + (size_t)t * 4;

    float4 v[NS];
    #pragma unroll
    for (int j = 0; j < NS; ++j)
        v[j] = *reinterpret_cast<const float4*>(params + base + (size_t)j * NP);

    #pragma unroll
    for (int i = 0; i < NS; ++i) {
        float4 acc = make_float4(0.f, 0.f, 0.f, 0.f);
        #pragma unroll
        for (int j = 0; j < NS; ++j) {
            const float wij = ws[i][j];   // LDS broadcast, conflict-free
            acc.x = fmaf(wij, v[j].x, acc.x);
            acc.y = fmaf(wij, v[j].y, acc.y);
            acc.z = fmaf(wij, v[j].z, acc.z);
            acc.w = fmaf(wij, v[j].w, acc.w);
        }
        *reinterpret_cast<float4*>(out + base + (size_t)i * NP) = acc;
    }
}

extern "C" void kernel_launch(void* const* d_in, const int* in_sizes, int n_in,
                              void* d_out, int out_size, void* d_ws, size_t ws_size,
                              hipStream_t stream) {
    const float* reps   = (const float*)d_in[0];   // [64,16,256]  f32
    const float* params = (const float*)d_in[1];   // [64,16,65536] f32
    float* out = (float*)d_out;                    // [64,16,65536] f32
    float* w   = (float*)d_ws;                     // [64,16,16]    f32 scratch (64 KiB)

    hipLaunchKernelGGL(coexpert_weights, dim3(NC), dim3(256), 0, stream, reps, w);

    dim3 grid(NP / 1024, NC);                      // (64, 64)
    hipLaunchKernelGGL(coexpert_agg, grid, dim3(256), 0, stream, params, w, out);
}

// Round 5
// 105.156 us; speedup vs baseline: 1.0985x; 1.0985x over previous
//
#include <hip/hip_runtime.h>
#include <hip/hip_bf16.h>

// Problem constants (fixed by setup_inputs): C=64 cliques, S=16, D=256, P=65536
#define NC 64
#define NS 16
#define ND 256
#define NP 65536
#define EPS 1e-8f

typedef float f4 __attribute__((ext_vector_type(4)));

// ---------------------------------------------------------------------------
// Kernel 1: per-clique cosine-similarity attention weights.
// One block per clique, 256 threads; thread t = i*16 + j computes dot(x_i,x_j).
// Row softmax via __shfl_xor within the 16-lane group.
// ---------------------------------------------------------------------------
__global__ __launch_bounds__(256) void coexpert_weights(
    const float* __restrict__ reps,   // [C, S, D]
    float* __restrict__ w)            // [C, S, S]
{
    const int c = blockIdx.x;
    const int t = threadIdx.x;

    __shared__ float xs[NS][ND];      // 16 KiB
    __shared__ float norms[NS];

    // Cooperative load of this clique's reps: 4096 floats / 256 threads.
    const float* xc = reps + (size_t)c * NS * ND;
    #pragma unroll
    for (int k = t; k < NS * ND; k += 256)
        xs[k >> 8][k & (ND - 1)] = xc[k];
    __syncthreads();

    const int i = t >> 4;
    const int j = t & 15;

    // dot(x_i, x_j) with float4 LDS reads
    float dot = 0.f;
    #pragma unroll 8
    for (int d = 0; d < ND; d += 4) {
        f4 a = *reinterpret_cast<const f4*>(&xs[i][d]);
        f4 b = *reinterpret_cast<const f4*>(&xs[j][d]);
        dot += a.x * b.x + a.y * b.y + a.z * b.z + a.w * b.w;
    }

    // Diagonal threads publish norms.
    if (i == j) norms[i] = sqrtf(dot);
    __syncthreads();

    float sim = dot / (norms[i] * norms[j] + EPS);

    // Row softmax over j (16-lane group reduce; xor masks < 16 stay in-group).
    float m = sim;
    #pragma unroll
    for (int off = 1; off < 16; off <<= 1)
        m = fmaxf(m, __shfl_xor(m, off));
    float e = expf(sim - m);
    float s = e;
    #pragma unroll
    for (int off = 1; off < 16; off <<= 1)
        s += __shfl_xor(s, off);

    w[(size_t)c * NS * NS + t] = e / s;
}

// ---------------------------------------------------------------------------
// Kernel 2: out[c,i,p] = sum_j w[c,i,j] * params[c,j,p]
// Pure streaming (read-once / write-once): non-temporal loads & stores to
// bypass L2/L3 allocation. Each thread owns 4 consecutive p's (float4);
// perfectly coalesced 1 KiB/wave per access.
// ---------------------------------------------------------------------------
__global__ __launch_bounds__(256) void coexpert_agg(
    const float* __restrict__ params, // [C, S, P]
    const float* __restrict__ w,      // [C, S, S]
    float* __restrict__ out)          // [C, S, P]
{
    const int chunk = blockIdx.x;     // 64 chunks of 1024 p's
    const int c     = blockIdx.y;     // 64 cliques
    const int t     = threadIdx.x;

    __shared__ float ws[NS][NS];
    ws[t >> 4][t & 15] = w[(size_t)c * NS * NS + t];
    __syncthreads();

    const size_t base = (size_t)c * NS * NP + (size_t)chunk * 1024 + (size_t)t * 4;
    const f4* pin  = reinterpret_cast<const f4*>(params + base);  // stride NP/4 f4's
    f4*       pout = reinterpret_cast<f4*>(out + base);

    f4 v[NS];
    #pragma unroll
    for (int j = 0; j < NS; ++j)
        v[j] = __builtin_nontemporal_load(pin + (size_t)j * (NP / 4));

    #pragma unroll
    for (int i = 0; i < NS; ++i) {
        f4 acc = (f4)(0.f);
        #pragma unroll
        for (int j = 0; j < NS; ++j)
            acc += ws[i][j] * v[j];   // LDS broadcast, conflict-free
        __builtin_nontemporal_store(acc, pout + (size_t)i * (NP / 4));
    }
}

extern "C" void kernel_launch(void* const* d_in, const int* in_sizes, int n_in,
                              void* d_out, int out_size, void* d_ws, size_t ws_size,
                              hipStream_t stream) {
    const float* reps   = (const float*)d_in[0];   // [64,16,256]  f32
    const float* params = (const float*)d_in[1];   // [64,16,65536] f32
    float* out = (float*)d_out;                    // [64,16,65536] f32
    float* w   = (float*)d_ws;                     // [64,16,16]    f32 scratch (64 KiB)

    hipLaunchKernelGGL(coexpert_weights, dim3(NC), dim3(256), 0, stream, reps, w);

    dim3 grid(NP / 1024, NC);                      // (64, 64)
    hipLaunchKernelGGL(coexpert_agg, grid, dim3(256), 0, stream, params, w, out);
}